// Round 1
// baseline (1407.795 us; speedup 1.0000x reference)
//
#include <hip/hip_runtime.h>
#include <cstddef>
#include <cstdint>

// Problem constants (B=16, S=1024, D=768, DC=64, K=8192)
#define NROW   16384
#define DMODEL 768
#define DCODE  64
#define KCODES 8192

// d_out layout (float element offsets): [out 16384*768][loss 1][codex 16384*8192]
#define OUT_LOSS  12582912
#define OUT_CODEX 12582913
// 16B-aligned scratch carved out of the codex region (zeroed at the end)
#define SCRATCH   12582916
#define H_OFF     (SCRATCH)
#define ZE_OFF    (SCRATCH + 12582912)
#define ZN_OFF    (ZE_OFF + 1048576)
#define Q_OFF     (ZN_OFF + 1048576)
#define P_OFF     (Q_OFF + 524288)

// ---------------------------------------------------------------------------
// Generic 128x128x16 fp32 tiled GEMM: C = act(A@B + bias)
// A: MxK row-major, B: KxN row-major. 256 threads, 8x8 micro-tile.
// ---------------------------------------------------------------------------
template <int TANH>
__global__ __launch_bounds__(256) void gemm128(const float* __restrict__ A,
                                               const float* __restrict__ B,
                                               const float* __restrict__ bias,
                                               float* __restrict__ C,
                                               int M, int N, int K) {
    __shared__ float As[16][128];   // transposed: As[k][m]
    __shared__ float Bs[16][128];   // natural:    Bs[k][n]
    const int t    = threadIdx.x;
    const int row0 = blockIdx.y * 128;
    const int col0 = blockIdx.x * 128;
    const int tx = t & 15, ty = t >> 4;
    const int ar = t >> 2, ac = (t & 3) << 2;
    const int br = t >> 5, bc = (t & 31) << 2;

    const float* Ap0 = A + (size_t)(row0 + ar) * K + ac;
    const float* Ap1 = Ap0 + (size_t)64 * K;
    const float* Bp0 = B + (size_t)br * N + col0 + bc;
    const float* Bp1 = Bp0 + (size_t)8 * N;

    float acc[8][8];
#pragma unroll
    for (int i = 0; i < 8; ++i)
#pragma unroll
        for (int j = 0; j < 8; ++j) acc[i][j] = 0.0f;

    for (int k0 = 0; k0 < K; k0 += 16) {
        float4 a0 = *reinterpret_cast<const float4*>(Ap0 + k0);
        float4 a1 = *reinterpret_cast<const float4*>(Ap1 + k0);
        float4 b0 = *reinterpret_cast<const float4*>(Bp0 + (size_t)k0 * N);
        float4 b1 = *reinterpret_cast<const float4*>(Bp1 + (size_t)k0 * N);
        __syncthreads();
        As[ac + 0][ar] = a0.x; As[ac + 1][ar] = a0.y;
        As[ac + 2][ar] = a0.z; As[ac + 3][ar] = a0.w;
        As[ac + 0][ar + 64] = a1.x; As[ac + 1][ar + 64] = a1.y;
        As[ac + 2][ar + 64] = a1.z; As[ac + 3][ar + 64] = a1.w;
        *reinterpret_cast<float4*>(&Bs[br][bc])     = b0;
        *reinterpret_cast<float4*>(&Bs[br + 8][bc]) = b1;
        __syncthreads();
#pragma unroll
        for (int k = 0; k < 16; ++k) {
            float4 xa0 = *reinterpret_cast<const float4*>(&As[k][ty << 2]);
            float4 xa1 = *reinterpret_cast<const float4*>(&As[k][(ty << 2) + 64]);
            float4 xb0 = *reinterpret_cast<const float4*>(&Bs[k][tx << 2]);
            float4 xb1 = *reinterpret_cast<const float4*>(&Bs[k][(tx << 2) + 64]);
            float av[8] = {xa0.x, xa0.y, xa0.z, xa0.w, xa1.x, xa1.y, xa1.z, xa1.w};
            float bv[8] = {xb0.x, xb0.y, xb0.z, xb0.w, xb1.x, xb1.y, xb1.z, xb1.w};
#pragma unroll
            for (int i = 0; i < 8; ++i)
#pragma unroll
                for (int j = 0; j < 8; ++j)
                    acc[i][j] = fmaf(av[i], bv[j], acc[i][j]);
        }
    }
#pragma unroll
    for (int i = 0; i < 8; ++i) {
        int r = row0 + (ty << 2) + (i & 3) + ((i & 4) << 4);
        float* Crow = C + (size_t)r * N;
#pragma unroll
        for (int jh = 0; jh < 2; ++jh) {
            int c = col0 + (tx << 2) + (jh << 6);
            float4 v;
            v.x = acc[i][jh * 4 + 0] + bias[c + 0];
            v.y = acc[i][jh * 4 + 1] + bias[c + 1];
            v.z = acc[i][jh * 4 + 2] + bias[c + 2];
            v.w = acc[i][jh * 4 + 3] + bias[c + 3];
            if (TANH) {
                v.x = tanhf(v.x); v.y = tanhf(v.y);
                v.z = tanhf(v.z); v.w = tanhf(v.w);
            }
            *reinterpret_cast<float4*>(Crow + c) = v;
        }
    }
}

// ---------------------------------------------------------------------------
// GEMM with N=64 (full DC per block): C = A@B + bias. BM=128, BK=16.
// 256 threads, 8x4 micro-tile.
// ---------------------------------------------------------------------------
__global__ __launch_bounds__(256) void gemm_n64(const float* __restrict__ A,
                                                const float* __restrict__ B,
                                                const float* __restrict__ bias,
                                                float* __restrict__ C, int K) {
    __shared__ float As[16][128];
    __shared__ float Bs[16][64];
    const int t    = threadIdx.x;
    const int row0 = blockIdx.x * 128;
    const int tx = t & 15, ty = t >> 4;
    const int ar = t >> 2, ac = (t & 3) << 2;
    const int br = t >> 4, bc = (t & 15) << 2;

    const float* Ap0 = A + (size_t)(row0 + ar) * K + ac;
    const float* Ap1 = Ap0 + (size_t)64 * K;
    const float* Bp0 = B + (size_t)br * 64 + bc;

    float acc[8][4];
#pragma unroll
    for (int i = 0; i < 8; ++i)
#pragma unroll
        for (int j = 0; j < 4; ++j) acc[i][j] = 0.0f;

    for (int k0 = 0; k0 < K; k0 += 16) {
        float4 a0 = *reinterpret_cast<const float4*>(Ap0 + k0);
        float4 a1 = *reinterpret_cast<const float4*>(Ap1 + k0);
        float4 b0 = *reinterpret_cast<const float4*>(Bp0 + (size_t)k0 * 64);
        __syncthreads();
        As[ac + 0][ar] = a0.x; As[ac + 1][ar] = a0.y;
        As[ac + 2][ar] = a0.z; As[ac + 3][ar] = a0.w;
        As[ac + 0][ar + 64] = a1.x; As[ac + 1][ar + 64] = a1.y;
        As[ac + 2][ar + 64] = a1.z; As[ac + 3][ar + 64] = a1.w;
        *reinterpret_cast<float4*>(&Bs[br][bc]) = b0;
        __syncthreads();
#pragma unroll
        for (int k = 0; k < 16; ++k) {
            float4 xa0 = *reinterpret_cast<const float4*>(&As[k][ty << 2]);
            float4 xa1 = *reinterpret_cast<const float4*>(&As[k][(ty << 2) + 64]);
            float4 xb  = *reinterpret_cast<const float4*>(&Bs[k][tx << 2]);
            float av[8] = {xa0.x, xa0.y, xa0.z, xa0.w, xa1.x, xa1.y, xa1.z, xa1.w};
            float bv[4] = {xb.x, xb.y, xb.z, xb.w};
#pragma unroll
            for (int i = 0; i < 8; ++i)
#pragma unroll
                for (int j = 0; j < 4; ++j)
                    acc[i][j] = fmaf(av[i], bv[j], acc[i][j]);
        }
    }
    const int c = tx << 2;
#pragma unroll
    for (int i = 0; i < 8; ++i) {
        int r = row0 + (ty << 2) + (i & 3) + ((i & 4) << 4);
        float4 v;
        v.x = acc[i][0] + bias[c + 0];
        v.y = acc[i][1] + bias[c + 1];
        v.z = acc[i][2] + bias[c + 2];
        v.w = acc[i][3] + bias[c + 3];
        *reinterpret_cast<float4*>(C + (size_t)r * 64 + c) = v;
    }
}

// ---------------------------------------------------------------------------
// Row-wise l2 normalize (DC=64): one wave per row.
// ---------------------------------------------------------------------------
__global__ __launch_bounds__(256) void l2norm_k(const float* __restrict__ Ze,
                                                float* __restrict__ Zn) {
    const int t = threadIdx.x;
    const int lane = t & 63;
    const int n = blockIdx.x * 4 + (t >> 6);
    float v = Ze[(size_t)n * 64 + lane];
    float ss = v * v;
#pragma unroll
    for (int off = 32; off > 0; off >>= 1) ss += __shfl_xor(ss, off, 64);
    float nrm = sqrtf(ss);
    Zn[(size_t)n * 64 + lane] = v / fmaxf(nrm, 1e-12f);
}

// ---------------------------------------------------------------------------
// Q = LayerNorm(emb) * gamma + beta  (per 64-wide row): one wave per row.
// ---------------------------------------------------------------------------
__global__ __launch_bounds__(256) void qln_k(const float* __restrict__ emb,
                                             const float* __restrict__ gamma,
                                             const float* __restrict__ beta,
                                             float* __restrict__ Q) {
    const int t = threadIdx.x;
    const int lane = t & 63;
    const int n = blockIdx.x * 4 + (t >> 6);
    float x = emb[(size_t)n * 64 + lane];
    float mu = x;
#pragma unroll
    for (int off = 32; off > 0; off >>= 1) mu += __shfl_xor(mu, off, 64);
    mu *= (1.0f / 64.0f);
    float d = x - mu;
    float var = d * d;
#pragma unroll
    for (int off = 32; off > 0; off >>= 1) var += __shfl_xor(var, off, 64);
    var *= (1.0f / 64.0f);
    float q = d / sqrtf(var + 1e-5f) * gamma[lane] + beta[lane];
    Q[(size_t)n * 64 + lane] = q;
}

// ---------------------------------------------------------------------------
// Argmax over codes: GEMM (M=16384, N=8192, K=64) with argmax epilogue.
// Grid (128 row-blocks, 8 code-splits); each block: 128 rows x 1024 codes.
// Writes per-(row,split) best (val, idx) partials.
// ---------------------------------------------------------------------------
__global__ __launch_bounds__(256) void argmax_k(const float* __restrict__ Zn,
                                                const float* __restrict__ emb,
                                                float* __restrict__ pval,
                                                int* __restrict__ pidx) {
    __shared__ float As[64][128];   // As[k][m]
    __shared__ float Bs[64][128];   // Bs[k][n]
    const int t     = threadIdx.x;
    const int row0  = blockIdx.x * 128;
    const int split = blockIdx.y;
    const int tx = t & 15, ty = t >> 4;
    const int lr = t >> 4;           // 0..15
    const int lk = (t & 15) << 2;    // 0..60

#pragma unroll
    for (int l = 0; l < 8; ++l) {
        int r = lr + l * 16;
        float4 a = *reinterpret_cast<const float4*>(&Zn[(size_t)(row0 + r) * 64 + lk]);
        As[lk + 0][r] = a.x; As[lk + 1][r] = a.y;
        As[lk + 2][r] = a.z; As[lk + 3][r] = a.w;
    }

    float bval[8];
    int   bidx[8];
#pragma unroll
    for (int i = 0; i < 8; ++i) { bval[i] = -3.0e38f; bidx[i] = 0; }

    for (int chunk = 0; chunk < 8; ++chunk) {
        const int code0 = split * 1024 + chunk * 128;
        __syncthreads();
#pragma unroll
        for (int l = 0; l < 8; ++l) {
            int r = lr + l * 16;
            float4 b = *reinterpret_cast<const float4*>(&emb[(size_t)(code0 + r) * 64 + lk]);
            Bs[lk + 0][r] = b.x; Bs[lk + 1][r] = b.y;
            Bs[lk + 2][r] = b.z; Bs[lk + 3][r] = b.w;
        }
        __syncthreads();

        float acc[8][8];
#pragma unroll
        for (int i = 0; i < 8; ++i)
#pragma unroll
            for (int j = 0; j < 8; ++j) acc[i][j] = 0.0f;

#pragma unroll 8
        for (int k = 0; k < 64; ++k) {
            float4 xa0 = *reinterpret_cast<const float4*>(&As[k][ty << 2]);
            float4 xa1 = *reinterpret_cast<const float4*>(&As[k][(ty << 2) + 64]);
            float4 xb0 = *reinterpret_cast<const float4*>(&Bs[k][tx << 2]);
            float4 xb1 = *reinterpret_cast<const float4*>(&Bs[k][(tx << 2) + 64]);
            float av[8] = {xa0.x, xa0.y, xa0.z, xa0.w, xa1.x, xa1.y, xa1.z, xa1.w};
            float bv[8] = {xb0.x, xb0.y, xb0.z, xb0.w, xb1.x, xb1.y, xb1.z, xb1.w};
#pragma unroll
            for (int i = 0; i < 8; ++i)
#pragma unroll
                for (int j = 0; j < 8; ++j)
                    acc[i][j] = fmaf(av[i], bv[j], acc[i][j]);
        }
        // update per-row bests; codes ascending within thread, strict > keeps
        // the lowest index on exact ties (numpy argmax semantics)
#pragma unroll
        for (int j = 0; j < 8; ++j) {
            int code = code0 + (tx << 2) + (j & 3) + ((j & 4) << 4);
#pragma unroll
            for (int i = 0; i < 8; ++i)
                if (acc[i][j] > bval[i]) { bval[i] = acc[i][j]; bidx[i] = code; }
        }
    }

    // reduce 16 tx-candidates per row via LDS
    __syncthreads();
    float* vs = &As[0][0];
    int*   is = reinterpret_cast<int*>(&Bs[0][0]);
#pragma unroll
    for (int i = 0; i < 8; ++i) {
        int r = (ty << 2) + (i & 3) + ((i & 4) << 4);
        vs[r * 16 + tx] = bval[i];
        is[r * 16 + tx] = bidx[i];
    }
    __syncthreads();
    if (t < 128) {
        float bv = vs[t * 16];
        int   bi = is[t * 16];
#pragma unroll
        for (int x = 1; x < 16; ++x) {
            float v  = vs[t * 16 + x];
            int   ii = is[t * 16 + x];
            if (v > bv || (v == bv && ii < bi)) { bv = v; bi = ii; }
        }
        pval[(size_t)(row0 + t) * 8 + split] = bv;
        pidx[(size_t)(row0 + t) * 8 + split] = bi;
    }
}

// Merge 8 split-partials per row -> final idx.
__global__ __launch_bounds__(256) void merge_k(const float* __restrict__ pval,
                                               const int* __restrict__ pidx,
                                               int* __restrict__ idx) {
    const int n = blockIdx.x * 256 + threadIdx.x;
    float bv = pval[(size_t)n * 8];
    int   bi = pidx[(size_t)n * 8];
#pragma unroll
    for (int s = 1; s < 8; ++s) {
        float v  = pval[(size_t)n * 8 + s];
        int   ii = pidx[(size_t)n * 8 + s];
        if (v > bv || (v == bv && ii < bi)) { bv = v; bi = ii; }
    }
    idx[n] = bi;
}

// out[n,:] = P[idx[n],:]   (768 floats = 192 float4 per row)
__global__ __launch_bounds__(192) void gather_k(const int* __restrict__ idx,
                                                const float* __restrict__ P,
                                                float* __restrict__ out) {
    const int r = blockIdx.x;
    const int t = threadIdx.x;
    const int k = idx[r];
    float4 v = *reinterpret_cast<const float4*>(&P[(size_t)k * 768 + t * 4]);
    *reinterpret_cast<float4*>(&out[(size_t)r * 768 + t * 4]) = v;
}

// loss += ||emb[idx[n]] - Zn[n]||^2 / (NROW*DCODE): one wave per row.
__global__ __launch_bounds__(256) void loss_k(const float* __restrict__ Zn,
                                              const float* __restrict__ emb,
                                              const int* __restrict__ idx,
                                              float* __restrict__ loss) {
    const int t = threadIdx.x;
    const int lane = t & 63;
    const int n = blockIdx.x * 4 + (t >> 6);
    float d = Zn[(size_t)n * 64 + lane] - emb[(size_t)idx[n] * 64 + lane];
    float s = d * d;
#pragma unroll
    for (int off = 32; off > 0; off >>= 1) s += __shfl_xor(s, off, 64);
    if (lane == 0) atomicAdd(loss, s * (1.0f / (16384.0f * 64.0f)));
}

// codex_probs one-hot scatter (region pre-zeroed).
__global__ __launch_bounds__(256) void scatter_k(const int* __restrict__ idx,
                                                 float* __restrict__ codex) {
    const int n = blockIdx.x * 256 + threadIdx.x;
    codex[(size_t)n * 8192 + idx[n]] = 1.0f;
}

// ---------------------------------------------------------------------------
extern "C" void kernel_launch(void* const* d_in, const int* in_sizes, int n_in,
                              void* d_out, int out_size, void* d_ws, size_t ws_size,
                              hipStream_t stream) {
    const float* Z     = (const float*)d_in[0];
    const float* W1    = (const float*)d_in[1];
    const float* b1    = (const float*)d_in[2];
    const float* W2    = (const float*)d_in[3];
    const float* b2    = (const float*)d_in[4];
    const float* emb   = (const float*)d_in[5];
    const float* gamma = (const float*)d_in[6];
    const float* beta  = (const float*)d_in[7];
    const float* Wp    = (const float*)d_in[8];
    const float* bp    = (const float*)d_in[9];

    float* outF  = (float*)d_out;
    float* H     = outF + H_OFF;
    float* Ze    = outF + ZE_OFF;
    float* Zn    = outF + ZN_OFF;
    float* Q     = outF + Q_OFF;
    float* P     = outF + P_OFF;
    float* lossp = outF + OUT_LOSS;
    float* codex = outF + OUT_CODEX;

    float* pval = (float*)d_ws;                       // 16384*8 floats
    int*   pidx = (int*)((char*)d_ws + 524288);       // 16384*8 ints
    int*   idxp = (int*)((char*)d_ws + 1048576);      // 16384 ints

    // zero the loss accumulator slot
    hipMemsetAsync((void*)lossp, 0, 4, stream);

    // 1) H = tanh(Z @ W1 + b1)           (16384 x 768, K=768)
    gemm128<1><<<dim3(6, 128), 256, 0, stream>>>(Z, W1, b1, H, NROW, DMODEL, DMODEL);
    // 2) Ze = H @ W2 + b2                (16384 x 64, K=768)
    gemm_n64<<<128, 256, 0, stream>>>(H, W2, b2, Ze, DMODEL);
    // 3) Zn = l2norm(Ze)
    l2norm_k<<<4096, 256, 0, stream>>>(Ze, Zn);
    // 4) Q = LN(emb)*gamma+beta          (8192 x 64)
    qln_k<<<2048, 256, 0, stream>>>(emb, gamma, beta, Q);
    // 5) P = Q @ Wp + bp                 (8192 x 768, K=64)
    gemm128<0><<<dim3(6, 64), 256, 0, stream>>>(Q, Wp, bp, P, KCODES, DMODEL, DCODE);
    // 6) per-(row,split) argmax partials over 8192 codes
    argmax_k<<<dim3(128, 8), 256, 0, stream>>>(Zn, emb, pval, pidx);
    // 7) merge partials -> idx
    merge_k<<<64, 256, 0, stream>>>(pval, pidx, idxp);
    // 8) out[n] = P[idx[n]]
    gather_k<<<16384, 192, 0, stream>>>(idxp, P, outF);
    // 9) commitment loss
    loss_k<<<4096, 256, 0, stream>>>(Zn, emb, idxp, lossp);
    // 10) zero codex region (also wipes scratch), then scatter the one-hots
    hipMemsetAsync((void*)codex, 0, (size_t)(out_size - OUT_CODEX) * sizeof(float), stream);
    scatter_k<<<64, 256, 0, stream>>>(idxp, codex);
}

// Round 4
// 1269.502 us; speedup vs baseline: 1.1089x; 1.1089x over previous
//
#include <hip/hip_runtime.h>
#include <cstddef>
#include <cstdint>

typedef unsigned short u16;
typedef short bf16x8 __attribute__((ext_vector_type(8)));
typedef float f32x4 __attribute__((ext_vector_type(4)));

// Problem constants (B=16, S=1024, D=768, DC=64, K=8192)
#define NROW   16384
#define DMODEL 768
#define DCODE  64
#define KCODES 8192

// d_out layout (float element offsets): [out 16384*768][loss 1][codex 16384*8192]
#define OUT_LOSS  12582912
#define OUT_CODEX 12582913
// 16B-aligned scratch carved out of the codex region (fully overwritten by the
// one-hot writer at the end). All offsets in float units, multiples of 4.
#define S0        12582916
#define H_OFF     (S0)                        // 12582912 f
#define P_OFF     (H_OFF + 12582912)          // 6291456 f
#define ZN_OFF    (P_OFF + 6291456)           // 1048576 f
#define Q_OFF     (ZN_OFF + 1048576)          // 524288 f
#define ZH_OFF    (Q_OFF + 524288)            // u16 planes of Z: each 12582912 u16 = 6291456 f
#define ZM_OFF    (ZH_OFF + 6291456)
#define ZL_OFF    (ZM_OFF + 6291456)
#define W1H_OFF   (ZL_OFF + 6291456)          // W1^T planes: each 589824 u16 = 294912 f
#define W1M_OFF   (W1H_OFF + 294912)
#define W1L_OFF   (W1M_OFF + 294912)
#define NH_OFF    (W1L_OFF + 294912)          // Zn planes: each 1048576 u16 = 524288 f
#define NM_OFF    (NH_OFF + 524288)
#define NL_OFF    (NM_OFF + 524288)
#define EH_OFF    (NL_OFF + 524288)           // emb planes: each 524288 u16 = 262144 f
#define EM_OFF    (EH_OFF + 262144)
#define EL_OFF    (EM_OFF + 262144)

__device__ __forceinline__ u16 f2bf(float x) {
    unsigned u = __float_as_uint(x);
    u += 0x7fffu + ((u >> 16) & 1u);          // RTNE
    return (u16)(u >> 16);
}
__device__ __forceinline__ float bf2f(u16 h) {
    return __uint_as_float(((unsigned)h) << 16);
}

// ---------------------------------------------------------------------------
// Split Z (fp32, 16384x768) into 3 bf16 planes (hi/mid/lo), elementwise x8.
// ---------------------------------------------------------------------------
__global__ __launch_bounds__(256) void split_z(const float* __restrict__ Z,
                                               u16* __restrict__ Ph,
                                               u16* __restrict__ Pm,
                                               u16* __restrict__ Pl) {
    const size_t g = (size_t)blockIdx.x * 256 + threadIdx.x;   // x8 elements
    const float4* zp = reinterpret_cast<const float4*>(Z) + g * 2;
    float4 a = zp[0], b = zp[1];
    float xs[8] = {a.x, a.y, a.z, a.w, b.x, b.y, b.z, b.w};
    union { u16 u[8]; uint4 v; } ph, pm, pl;
#pragma unroll
    for (int k = 0; k < 8; ++k) {
        float x = xs[k];
        u16 h = f2bf(x); float r = x - bf2f(h);
        u16 m = f2bf(r); float r2 = r - bf2f(m);
        u16 l = f2bf(r2);
        ph.u[k] = h; pm.u[k] = m; pl.u[k] = l;
    }
    *reinterpret_cast<uint4*>(Ph + g * 8) = ph.v;
    *reinterpret_cast<uint4*>(Pm + g * 8) = pm.v;
    *reinterpret_cast<uint4*>(Pl + g * 8) = pl.v;
}

// ---------------------------------------------------------------------------
// Split + transpose W1 (768x768): planes are W1^T [n][k] so B fragments read
// contiguous k. 32x32 LDS tile transpose.
// ---------------------------------------------------------------------------
__global__ __launch_bounds__(256) void split_w1t(const float* __restrict__ W1,
                                                 u16* __restrict__ Th,
                                                 u16* __restrict__ Tm,
                                                 u16* __restrict__ Tl) {
    __shared__ float tile[32][33];
    const int t = threadIdx.x;
    const int tc = t & 31, tr = t >> 5;          // tr 0..7
    const int k0 = blockIdx.y * 32, n0 = blockIdx.x * 32;
#pragma unroll
    for (int rr = 0; rr < 4; ++rr) {
        int r = tr * 4 + rr;
        tile[r][tc] = W1[(size_t)(k0 + r) * 768 + n0 + tc];
    }
    __syncthreads();
#pragma unroll
    for (int rr = 0; rr < 4; ++rr) {
        int n = n0 + tr * 4 + rr;
        int k = k0 + tc;
        float x = tile[tc][tr * 4 + rr];
        u16 h = f2bf(x); float r = x - bf2f(h);
        u16 m = f2bf(r); u16 l = f2bf(r - bf2f(m));
        Th[(size_t)n * 768 + k] = h;
        Tm[(size_t)n * 768 + k] = m;
        Tl[(size_t)n * 768 + k] = l;
    }
}

// ---------------------------------------------------------------------------
// One pass over emb (8192x64): write raw-emb bf16 splits (for sim MFMA) and
// Q = LN(emb)*gamma+beta (fp32, for the P projection). One wave per row.
// ---------------------------------------------------------------------------
__global__ __launch_bounds__(256) void qln_emb(const float* __restrict__ emb,
                                               const float* __restrict__ gamma,
                                               const float* __restrict__ beta,
                                               u16* __restrict__ Eh,
                                               u16* __restrict__ Em,
                                               u16* __restrict__ El,
                                               float* __restrict__ Q) {
    const int t = threadIdx.x;
    const int lane = t & 63;
    const int n = blockIdx.x * 4 + (t >> 6);
    float x = emb[(size_t)n * 64 + lane];
    u16 h = f2bf(x); float r = x - bf2f(h);
    u16 m = f2bf(r); u16 l = f2bf(r - bf2f(m));
    Eh[(size_t)n * 64 + lane] = h;
    Em[(size_t)n * 64 + lane] = m;
    El[(size_t)n * 64 + lane] = l;
    float mu = x;
#pragma unroll
    for (int off = 32; off > 0; off >>= 1) mu += __shfl_xor(mu, off, 64);
    mu *= (1.0f / 64.0f);
    float d = x - mu;
    float var = d * d;
#pragma unroll
    for (int off = 32; off > 0; off >>= 1) var += __shfl_xor(var, off, 64);
    var *= (1.0f / 64.0f);
    Q[(size_t)n * 64 + lane] = d * rsqrtf(var + 1e-5f) * gamma[lane] + beta[lane];
}

// ---------------------------------------------------------------------------
// GEMM1 via 6-product bf16x3 MFMA: H = tanh(Z @ W1 + b1).
// M=16384, N=768, K=768. BM=128, BN=128, BK=32. LDS 61440 B.
// Each wave owns a disjoint 64x64 quadrant -> no cross-wave write overlap.
// 16x16x32 MFMA; A[m=lane&15][k=q*8+j], B[k=q*8+j][n=lane&15] (W1^T rows),
// C/D: col=lane&15, row=q*4+reg (guide-verified m89/m91/m120).
// ---------------------------------------------------------------------------
#define G1S 40   // LDS row stride in u16 (32 + 8 pad): 80 B, 16B-aligned
__global__ __launch_bounds__(256, 2) void gemm1_mfma(
        const u16* __restrict__ Ah0, const u16* __restrict__ Am0, const u16* __restrict__ Al0,
        const u16* __restrict__ Bh0, const u16* __restrict__ Bm0, const u16* __restrict__ Bl0,
        const float* __restrict__ bias, float* __restrict__ H) {
    __shared__ u16 lds[6 * 128 * G1S];    // 61440 B
    u16* As = lds;                        // 3 planes x [128][G1S]
    u16* Bs = lds + 3 * 128 * G1S;        // 3 planes x [128][G1S]

    const int row0 = blockIdx.y * 128, col0 = blockIdx.x * 128;
    const int t = threadIdx.x;
    const int w = t >> 6, lane = t & 63, lm = lane & 15, q = lane >> 4;
    const int wr = (w >> 1) * 64, wc = (w & 1) * 64;

    const u16* Ap[3] = {Ah0, Am0, Al0};
    const u16* Bp[3] = {Bh0, Bm0, Bl0};

    f32x4 acc[4][4];
#pragma unroll
    for (int i = 0; i < 4; ++i)
#pragma unroll
        for (int j = 0; j < 4; ++j) acc[i][j] = (f32x4){0.f, 0.f, 0.f, 0.f};

    const int srow = t >> 2;           // 0..63
    const int sc8 = (t & 3) * 8;       // 0,8,16,24

    for (int k0 = 0; k0 < 768; k0 += 32) {
        __syncthreads();
#pragma unroll
        for (int p = 0; p < 3; ++p) {
            u16* ap = As + p * 128 * G1S;
            u16* bp = Bs + p * 128 * G1S;
            *reinterpret_cast<uint4*>(ap + srow * G1S + sc8) =
                *reinterpret_cast<const uint4*>(Ap[p] + (size_t)(row0 + srow) * 768 + k0 + sc8);
            *reinterpret_cast<uint4*>(ap + (srow + 64) * G1S + sc8) =
                *reinterpret_cast<const uint4*>(Ap[p] + (size_t)(row0 + srow + 64) * 768 + k0 + sc8);
            *reinterpret_cast<uint4*>(bp + srow * G1S + sc8) =
                *reinterpret_cast<const uint4*>(Bp[p] + (size_t)(col0 + srow) * 768 + k0 + sc8);
            *reinterpret_cast<uint4*>(bp + (srow + 64) * G1S + sc8) =
                *reinterpret_cast<const uint4*>(Bp[p] + (size_t)(col0 + srow + 64) * 768 + k0 + sc8);
        }
        __syncthreads();

        bf16x8 fah[4], fam[4], fal[4];
#pragma unroll
        for (int i = 0; i < 4; ++i) {
            int off = (wr + i * 16 + lm) * G1S + q * 8;
            fah[i] = *reinterpret_cast<const bf16x8*>(As + 0 * 128 * G1S + off);
            fam[i] = *reinterpret_cast<const bf16x8*>(As + 1 * 128 * G1S + off);
            fal[i] = *reinterpret_cast<const bf16x8*>(As + 2 * 128 * G1S + off);
        }
#pragma unroll
        for (int j = 0; j < 4; ++j) {
            int offb = (wc + j * 16 + lm) * G1S + q * 8;
            bf16x8 fbh = *reinterpret_cast<const bf16x8*>(Bs + 0 * 128 * G1S + offb);
            bf16x8 fbm = *reinterpret_cast<const bf16x8*>(Bs + 1 * 128 * G1S + offb);
            bf16x8 fbl = *reinterpret_cast<const bf16x8*>(Bs + 2 * 128 * G1S + offb);
#pragma unroll
            for (int i = 0; i < 4; ++i) {
                f32x4 c = acc[i][j];
                c = __builtin_amdgcn_mfma_f32_16x16x32_bf16(fah[i], fbl, c, 0, 0, 0);
                c = __builtin_amdgcn_mfma_f32_16x16x32_bf16(fal[i], fbh, c, 0, 0, 0);
                c = __builtin_amdgcn_mfma_f32_16x16x32_bf16(fam[i], fbm, c, 0, 0, 0);
                c = __builtin_amdgcn_mfma_f32_16x16x32_bf16(fah[i], fbm, c, 0, 0, 0);
                c = __builtin_amdgcn_mfma_f32_16x16x32_bf16(fam[i], fbh, c, 0, 0, 0);
                c = __builtin_amdgcn_mfma_f32_16x16x32_bf16(fah[i], fbh, c, 0, 0, 0);
                acc[i][j] = c;
            }
        }
    }
    // epilogue: +bias, tanh, store
#pragma unroll
    for (int i = 0; i < 4; ++i)
#pragma unroll
        for (int j = 0; j < 4; ++j) {
            int col = col0 + wc + j * 16 + lm;
            float bv = bias[col];
#pragma unroll
            for (int r = 0; r < 4; ++r) {
                int row = row0 + wr + i * 16 + q * 4 + r;
                H[(size_t)row * 768 + col] = tanhf(acc[i][j][r] + bv);
            }
        }
}

// ---------------------------------------------------------------------------
// GEMM2 fused with l2norm: Zn = l2norm(H @ W2 + b2), also writes Zn bf16
// splits. M=16384, N=64(full), K=768. fp32 vector (small GEMM).
// ---------------------------------------------------------------------------
__global__ __launch_bounds__(256) void gemm2_l2(const float* __restrict__ A,
                                                const float* __restrict__ B,
                                                const float* __restrict__ bias,
                                                float* __restrict__ Zn,
                                                u16* __restrict__ Nh,
                                                u16* __restrict__ Nm,
                                                u16* __restrict__ Nl) {
    __shared__ float As[16][128];
    __shared__ float Bs[16][64];
    const int t    = threadIdx.x;
    const int row0 = blockIdx.x * 128;
    const int tx = t & 15, ty = t >> 4;
    const int ar = t >> 2, ac = (t & 3) << 2;
    const int br = t >> 4, bc = (t & 15) << 2;

    const float* Ap0 = A + (size_t)(row0 + ar) * 768 + ac;
    const float* Ap1 = Ap0 + (size_t)64 * 768;
    const float* Bp0 = B + (size_t)br * 64 + bc;

    float acc[8][4];
#pragma unroll
    for (int i = 0; i < 8; ++i)
#pragma unroll
        for (int j = 0; j < 4; ++j) acc[i][j] = 0.0f;

    for (int k0 = 0; k0 < 768; k0 += 16) {
        float4 a0 = *reinterpret_cast<const float4*>(Ap0 + k0);
        float4 a1 = *reinterpret_cast<const float4*>(Ap1 + k0);
        float4 b0 = *reinterpret_cast<const float4*>(Bp0 + (size_t)k0 * 64);
        __syncthreads();
        As[ac + 0][ar] = a0.x; As[ac + 1][ar] = a0.y;
        As[ac + 2][ar] = a0.z; As[ac + 3][ar] = a0.w;
        As[ac + 0][ar + 64] = a1.x; As[ac + 1][ar + 64] = a1.y;
        As[ac + 2][ar + 64] = a1.z; As[ac + 3][ar + 64] = a1.w;
        *reinterpret_cast<float4*>(&Bs[br][bc]) = b0;
        __syncthreads();
#pragma unroll
        for (int k = 0; k < 16; ++k) {
            float4 xa0 = *reinterpret_cast<const float4*>(&As[k][ty << 2]);
            float4 xa1 = *reinterpret_cast<const float4*>(&As[k][(ty << 2) + 64]);
            float4 xb  = *reinterpret_cast<const float4*>(&Bs[k][tx << 2]);
            float av[8] = {xa0.x, xa0.y, xa0.z, xa0.w, xa1.x, xa1.y, xa1.z, xa1.w};
            float bv[4] = {xb.x, xb.y, xb.z, xb.w};
#pragma unroll
            for (int i = 0; i < 8; ++i)
#pragma unroll
                for (int j = 0; j < 4; ++j)
                    acc[i][j] = fmaf(av[i], bv[j], acc[i][j]);
        }
    }
    const int c = tx << 2;
    const float4 bv4 = *reinterpret_cast<const float4*>(bias + c);
#pragma unroll
    for (int i = 0; i < 8; ++i) {
        float v0 = acc[i][0] + bv4.x;
        float v1 = acc[i][1] + bv4.y;
        float v2 = acc[i][2] + bv4.z;
        float v3 = acc[i][3] + bv4.w;
        float ss = v0 * v0 + v1 * v1 + v2 * v2 + v3 * v3;
#pragma unroll
        for (int msk = 1; msk <= 8; msk <<= 1) ss += __shfl_xor(ss, msk, 64);
        float sc = 1.0f / fmaxf(sqrtf(ss), 1e-12f);
        v0 *= sc; v1 *= sc; v2 *= sc; v3 *= sc;
        int r = row0 + (ty << 2) + (i & 3) + ((i & 4) << 4);
        float4 z = {v0, v1, v2, v3};
        *reinterpret_cast<float4*>(Zn + (size_t)r * 64 + c) = z;
        float vs[4] = {v0, v1, v2, v3};
        u16 hu[4], mu_[4], lu[4];
#pragma unroll
        for (int j = 0; j < 4; ++j) {
            u16 h = f2bf(vs[j]); float rr = vs[j] - bf2f(h);
            u16 m = f2bf(rr);    u16 l = f2bf(rr - bf2f(m));
            hu[j] = h; mu_[j] = m; lu[j] = l;
        }
        ushort4 hh = make_ushort4(hu[0], hu[1], hu[2], hu[3]);
        ushort4 mm = make_ushort4(mu_[0], mu_[1], mu_[2], mu_[3]);
        ushort4 ll = make_ushort4(lu[0], lu[1], lu[2], lu[3]);
        *reinterpret_cast<ushort4*>(Nh + (size_t)r * 64 + c) = hh;
        *reinterpret_cast<ushort4*>(Nm + (size_t)r * 64 + c) = mm;
        *reinterpret_cast<ushort4*>(Nl + (size_t)r * 64 + c) = ll;
    }
}

// ---------------------------------------------------------------------------
// Generic 128x128x16 fp32 tiled GEMM (used for P = Q @ Wp + bp, K=64).
// ---------------------------------------------------------------------------
__global__ __launch_bounds__(256) void gemm128(const float* __restrict__ A,
                                               const float* __restrict__ B,
                                               const float* __restrict__ bias,
                                               float* __restrict__ C,
                                               int M, int N, int K) {
    __shared__ float As[16][128];
    __shared__ float Bs[16][128];
    const int t    = threadIdx.x;
    const int row0 = blockIdx.y * 128;
    const int col0 = blockIdx.x * 128;
    const int tx = t & 15, ty = t >> 4;
    const int ar = t >> 2, ac = (t & 3) << 2;
    const int br = t >> 5, bc = (t & 31) << 2;

    const float* Ap0 = A + (size_t)(row0 + ar) * K + ac;
    const float* Ap1 = Ap0 + (size_t)64 * K;
    const float* Bp0 = B + (size_t)br * N + col0 + bc;
    const float* Bp1 = Bp0 + (size_t)8 * N;

    float acc[8][8];
#pragma unroll
    for (int i = 0; i < 8; ++i)
#pragma unroll
        for (int j = 0; j < 8; ++j) acc[i][j] = 0.0f;

    for (int k0 = 0; k0 < K; k0 += 16) {
        float4 a0 = *reinterpret_cast<const float4*>(Ap0 + k0);
        float4 a1 = *reinterpret_cast<const float4*>(Ap1 + k0);
        float4 b0 = *reinterpret_cast<const float4*>(Bp0 + (size_t)k0 * N);
        float4 b1 = *reinterpret_cast<const float4*>(Bp1 + (size_t)k0 * N);
        __syncthreads();
        As[ac + 0][ar] = a0.x; As[ac + 1][ar] = a0.y;
        As[ac + 2][ar] = a0.z; As[ac + 3][ar] = a0.w;
        As[ac + 0][ar + 64] = a1.x; As[ac + 1][ar + 64] = a1.y;
        As[ac + 2][ar + 64] = a1.z; As[ac + 3][ar + 64] = a1.w;
        *reinterpret_cast<float4*>(&Bs[br][bc])     = b0;
        *reinterpret_cast<float4*>(&Bs[br + 8][bc]) = b1;
        __syncthreads();
#pragma unroll
        for (int k = 0; k < 16; ++k) {
            float4 xa0 = *reinterpret_cast<const float4*>(&As[k][ty << 2]);
            float4 xa1 = *reinterpret_cast<const float4*>(&As[k][(ty << 2) + 64]);
            float4 xb0 = *reinterpret_cast<const float4*>(&Bs[k][tx << 2]);
            float4 xb1 = *reinterpret_cast<const float4*>(&Bs[k][(tx << 2) + 64]);
            float av[8] = {xa0.x, xa0.y, xa0.z, xa0.w, xa1.x, xa1.y, xa1.z, xa1.w};
            float bv[8] = {xb0.x, xb0.y, xb0.z, xb0.w, xb1.x, xb1.y, xb1.z, xb1.w};
#pragma unroll
            for (int i = 0; i < 8; ++i)
#pragma unroll
                for (int j = 0; j < 8; ++j)
                    acc[i][j] = fmaf(av[i], bv[j], acc[i][j]);
        }
    }
#pragma unroll
    for (int i = 0; i < 8; ++i) {
        int r = row0 + (ty << 2) + (i & 3) + ((i & 4) << 4);
        float* Crow = C + (size_t)r * N;
#pragma unroll
        for (int jh = 0; jh < 2; ++jh) {
            int cc = col0 + (tx << 2) + (jh << 6);
            float4 v;
            v.x = acc[i][jh * 4 + 0] + bias[cc + 0];
            v.y = acc[i][jh * 4 + 1] + bias[cc + 1];
            v.z = acc[i][jh * 4 + 2] + bias[cc + 2];
            v.w = acc[i][jh * 4 + 3] + bias[cc + 3];
            *reinterpret_cast<float4*>(Crow + cc) = v;
        }
    }
}

// ---------------------------------------------------------------------------
// Sim + argmax via 6-product bf16x3 MFMA. Grid (128 row-blocks, 8 splits).
// Block: 128 rows x 1024 codes (8 chunks of 128). A-fragments resident in
// registers (K=64); B (emb planes) staged per chunk in padded LDS.
// RACE FIX (round 3 bug): waves (w&1)=0/1 cover the SAME rows but different
// column halves; their winners must be merged through LDS before the single
// per-(row,split) write. Round 2/3 both waves wrote the same slot -> half the
// codes were dropped nondeterministically (absmax ~1.13, varying per run).
// ---------------------------------------------------------------------------
#define AXS 72   // LDS row stride in u16 (64 + 8 pad): 144 B, 16B-aligned
__global__ __launch_bounds__(256, 2) void argmax_mfma(
        const u16* __restrict__ Zh, const u16* __restrict__ Zm, const u16* __restrict__ Zl,
        const u16* __restrict__ Eh, const u16* __restrict__ Em, const u16* __restrict__ El,
        float* __restrict__ pval, int* __restrict__ pidx) {
    __shared__ u16 Bs[3 * 128 * AXS];     // 55296 B
    __shared__ float sv[128][2];          // +1024 B
    __shared__ int   si[128][2];          // +1024 B  (total 57344 B)
    const int rb = blockIdx.x, split = blockIdx.y;
    const int row0 = rb * 128, cbase = split * 1024;
    const int t = threadIdx.x;
    const int w = t >> 6, lane = t & 63, lm = lane & 15, q = lane >> 4;
    const int wr = (w >> 1) * 64, wc = (w & 1) * 64;

    // Resident A fragments: [plane][mtile][kstep]
    bf16x8 a[3][4][2];
#pragma unroll
    for (int i = 0; i < 4; ++i) {
        int row = row0 + wr + i * 16 + lm;
#pragma unroll
        for (int ks = 0; ks < 2; ++ks) {
            size_t off = (size_t)row * 64 + ks * 32 + q * 8;
            a[0][i][ks] = *reinterpret_cast<const bf16x8*>(Zh + off);
            a[1][i][ks] = *reinterpret_cast<const bf16x8*>(Zm + off);
            a[2][i][ks] = *reinterpret_cast<const bf16x8*>(Zl + off);
        }
    }

    float bval[4][4];
    int   bidx[4][4];
#pragma unroll
    for (int i = 0; i < 4; ++i)
#pragma unroll
        for (int r = 0; r < 4; ++r) { bval[i][r] = -3.0e38f; bidx[i][r] = 0; }

    for (int c = 0; c < 8; ++c) {
        const int code0 = cbase + c * 128;
        __syncthreads();
#pragma unroll
        for (int p = 0; p < 3; ++p) {
            const u16* Ep = (p == 0) ? Eh : ((p == 1) ? Em : El);
            u16* bsp = Bs + p * 128 * AXS;
#pragma unroll
            for (int it = 0; it < 4; ++it) {
                int cid = t + it * 256;
                int rr = cid >> 3, c8 = (cid & 7) * 8;
                *reinterpret_cast<uint4*>(bsp + rr * AXS + c8) =
                    *reinterpret_cast<const uint4*>(Ep + (size_t)(code0 + rr) * 64 + c8);
            }
        }
        __syncthreads();
#pragma unroll
        for (int j = 0; j < 4; ++j) {
            int nb = (wc + j * 16 + lm) * AXS;
            bf16x8 eh0 = *reinterpret_cast<const bf16x8*>(Bs + 0 * 128 * AXS + nb + q * 8);
            bf16x8 eh1 = *reinterpret_cast<const bf16x8*>(Bs + 0 * 128 * AXS + nb + 32 + q * 8);
            bf16x8 em0 = *reinterpret_cast<const bf16x8*>(Bs + 1 * 128 * AXS + nb + q * 8);
            bf16x8 em1 = *reinterpret_cast<const bf16x8*>(Bs + 1 * 128 * AXS + nb + 32 + q * 8);
            bf16x8 el0 = *reinterpret_cast<const bf16x8*>(Bs + 2 * 128 * AXS + nb + q * 8);
            bf16x8 el1 = *reinterpret_cast<const bf16x8*>(Bs + 2 * 128 * AXS + nb + 32 + q * 8);
            int code = code0 + wc + j * 16 + lm;
#pragma unroll
            for (int i = 0; i < 4; ++i) {
                f32x4 s = (f32x4){0.f, 0.f, 0.f, 0.f};
                s = __builtin_amdgcn_mfma_f32_16x16x32_bf16(a[0][i][0], el0, s, 0, 0, 0);
                s = __builtin_amdgcn_mfma_f32_16x16x32_bf16(a[2][i][0], eh0, s, 0, 0, 0);
                s = __builtin_amdgcn_mfma_f32_16x16x32_bf16(a[1][i][0], em0, s, 0, 0, 0);
                s = __builtin_amdgcn_mfma_f32_16x16x32_bf16(a[0][i][0], em0, s, 0, 0, 0);
                s = __builtin_amdgcn_mfma_f32_16x16x32_bf16(a[1][i][0], eh0, s, 0, 0, 0);
                s = __builtin_amdgcn_mfma_f32_16x16x32_bf16(a[0][i][0], eh0, s, 0, 0, 0);
                s = __builtin_amdgcn_mfma_f32_16x16x32_bf16(a[0][i][1], el1, s, 0, 0, 0);
                s = __builtin_amdgcn_mfma_f32_16x16x32_bf16(a[2][i][1], eh1, s, 0, 0, 0);
                s = __builtin_amdgcn_mfma_f32_16x16x32_bf16(a[1][i][1], em1, s, 0, 0, 0);
                s = __builtin_amdgcn_mfma_f32_16x16x32_bf16(a[0][i][1], em1, s, 0, 0, 0);
                s = __builtin_amdgcn_mfma_f32_16x16x32_bf16(a[1][i][1], eh1, s, 0, 0, 0);
                s = __builtin_amdgcn_mfma_f32_16x16x32_bf16(a[0][i][1], eh1, s, 0, 0, 0);
#pragma unroll
                for (int r = 0; r < 4; ++r)
                    if (s[r] > bval[i][r]) { bval[i][r] = s[r]; bidx[i][r] = code; }
            }
        }
    }
    // reduce over the 16 lanes sharing each row (lm bits 0..3), then stash the
    // per-(row, column-half) winner in LDS
#pragma unroll
    for (int i = 0; i < 4; ++i)
#pragma unroll
        for (int r = 0; r < 4; ++r) {
            float v = bval[i][r];
            int   id = bidx[i][r];
#pragma unroll
            for (int msk = 1; msk <= 8; msk <<= 1) {
                float ov = __shfl_xor(v, msk, 64);
                int   oid = __shfl_xor(id, msk, 64);
                if (ov > v || (ov == v && oid < id)) { v = ov; id = oid; }
            }
            if (lm == 0) {
                int rl = wr + i * 16 + q * 4 + r;   // 0..127 within block
                sv[rl][w & 1] = v;
                si[rl][w & 1] = id;
            }
        }
    __syncthreads();
    // merge the two column-half winners and do the single write per row
    if (t < 128) {
        float v0 = sv[t][0], v1 = sv[t][1];
        int   i0 = si[t][0], i1 = si[t][1];
        float bv; int bi;
        if (v1 > v0 || (v1 == v0 && i1 < i0)) { bv = v1; bi = i1; }
        else                                  { bv = v0; bi = i0; }
        pval[(size_t)(row0 + t) * 8 + split] = bv;
        pidx[(size_t)(row0 + t) * 8 + split] = bi;
    }
}

// ---------------------------------------------------------------------------
// Exact fp32 rescore of the 8 split candidates per row -> final idx.
// One wave per row (4 rows/block); 8 lanes per candidate.
// ---------------------------------------------------------------------------
__global__ __launch_bounds__(256) void merge_rescore(const float* __restrict__ Zn,
                                                     const float* __restrict__ emb,
                                                     const int* __restrict__ pidx,
                                                     int* __restrict__ idx) {
    __shared__ float sv[4][8];
    __shared__ int   si[4][8];
    const int t = threadIdx.x;
    const int w = t >> 6, lane = t & 63;
    const int row = blockIdx.x * 4 + w;
    const int cg = lane >> 3, s = lane & 7;
    int cand = pidx[(size_t)row * 8 + cg];
    const float4* zp = reinterpret_cast<const float4*>(Zn + (size_t)row * 64 + s * 8);
    const float4* ep = reinterpret_cast<const float4*>(emb + (size_t)cand * 64 + s * 8);
    float4 z0 = zp[0], z1 = zp[1], e0 = ep[0], e1 = ep[1];
    float acc = z0.x * e0.x + z0.y * e0.y + z0.z * e0.z + z0.w * e0.w
              + z1.x * e1.x + z1.y * e1.y + z1.z * e1.z + z1.w * e1.w;
#pragma unroll
    for (int msk = 1; msk <= 4; msk <<= 1) acc += __shfl_xor(acc, msk, 64);
    if (s == 0) { sv[w][cg] = acc; si[w][cg] = cand; }
    __syncthreads();
    if (lane == 0) {
        float bv = sv[w][0];
        int   bi = si[w][0];
#pragma unroll
        for (int cc = 1; cc < 8; ++cc) {
            float v = sv[w][cc];
            int   ii = si[w][cc];
            if (v > bv || (v == bv && ii < bi)) { bv = v; bi = ii; }
        }
        idx[row] = bi;
    }
}

// out[n,:] = P[idx[n],:]
__global__ __launch_bounds__(192) void gather_k(const int* __restrict__ idx,
                                                const float* __restrict__ P,
                                                float* __restrict__ out) {
    const int r = blockIdx.x;
    const int t = threadIdx.x;
    const int k = idx[r];
    float4 v = *reinterpret_cast<const float4*>(&P[(size_t)k * 768 + t * 4]);
    *reinterpret_cast<float4*>(&out[(size_t)r * 768 + t * 4]) = v;
}

// loss += ||emb[idx[n]] - Zn[n]||^2 / (NROW*DCODE)
__global__ __launch_bounds__(256) void loss_k(const float* __restrict__ Zn,
                                              const float* __restrict__ emb,
                                              const int* __restrict__ idx,
                                              float* __restrict__ loss) {
    const int t = threadIdx.x;
    const int lane = t & 63;
    const int n = blockIdx.x * 4 + (t >> 6);
    float d = Zn[(size_t)n * 64 + lane] - emb[(size_t)idx[n] * 64 + lane];
    float s = d * d;
#pragma unroll
    for (int off = 32; off > 0; off >>= 1) s += __shfl_xor(s, off, 64);
    if (lane == 0) atomicAdd(loss, s * (1.0f / (16384.0f * 64.0f)));
}

// codex_probs: write the full one-hot matrix in one streaming pass.
__global__ __launch_bounds__(256) void onehot_k(const int* __restrict__ idx,
                                                float* __restrict__ codex) {
    const int row = blockIdx.x;
    const int k = idx[row];
    float* base = codex + (size_t)row * 8192;
#pragma unroll
    for (int it = 0; it < 8; ++it) {
        int col = it * 1024 + threadIdx.x * 4;
        float4 v = {0.f, 0.f, 0.f, 0.f};
        unsigned d = (unsigned)(k - col);
        if (d < 4u) (&v.x)[d] = 1.0f;
        *reinterpret_cast<float4*>(base + col) = v;
    }
}

// ---------------------------------------------------------------------------
extern "C" void kernel_launch(void* const* d_in, const int* in_sizes, int n_in,
                              void* d_out, int out_size, void* d_ws, size_t ws_size,
                              hipStream_t stream) {
    const float* Z     = (const float*)d_in[0];
    const float* W1    = (const float*)d_in[1];
    const float* b1    = (const float*)d_in[2];
    const float* W2    = (const float*)d_in[3];
    const float* b2    = (const float*)d_in[4];
    const float* emb   = (const float*)d_in[5];
    const float* gamma = (const float*)d_in[6];
    const float* beta  = (const float*)d_in[7];
    const float* Wp    = (const float*)d_in[8];
    const float* bp    = (const float*)d_in[9];

    float* outF  = (float*)d_out;
    float* H     = outF + H_OFF;
    float* P     = outF + P_OFF;
    float* Zn    = outF + ZN_OFF;
    float* Q     = outF + Q_OFF;
    u16*   ZH    = (u16*)(outF + ZH_OFF);
    u16*   ZM    = (u16*)(outF + ZM_OFF);
    u16*   ZL    = (u16*)(outF + ZL_OFF);
    u16*   W1H   = (u16*)(outF + W1H_OFF);
    u16*   W1M   = (u16*)(outF + W1M_OFF);
    u16*   W1L   = (u16*)(outF + W1L_OFF);
    u16*   NH    = (u16*)(outF + NH_OFF);
    u16*   NM    = (u16*)(outF + NM_OFF);
    u16*   NL    = (u16*)(outF + NL_OFF);
    u16*   EH    = (u16*)(outF + EH_OFF);
    u16*   EM    = (u16*)(outF + EM_OFF);
    u16*   EL    = (u16*)(outF + EL_OFF);
    float* lossp = outF + OUT_LOSS;
    float* codex = outF + OUT_CODEX;

    float* pval = (float*)d_ws;                       // 16384*8 floats
    int*   pidx = (int*)((char*)d_ws + 524288);       // 16384*8 ints
    int*   idxp = (int*)((char*)d_ws + 1048576);      // 16384 ints

    hipMemsetAsync((void*)lossp, 0, 4, stream);

    // splits / preprocessing
    split_z<<<6144, 256, 0, stream>>>(Z, ZH, ZM, ZL);
    split_w1t<<<dim3(24, 24), 256, 0, stream>>>(W1, W1H, W1M, W1L);
    qln_emb<<<2048, 256, 0, stream>>>(emb, gamma, beta, EH, EM, EL, Q);
    // H = tanh(Z @ W1 + b1)   (MFMA bf16x3, 6 products)
    gemm1_mfma<<<dim3(6, 128), 256, 0, stream>>>(ZH, ZM, ZL, W1H, W1M, W1L, b1, H);
    // Zn = l2norm(H @ W2 + b2) + bf16 splits
    gemm2_l2<<<128, 256, 0, stream>>>(H, W2, b2, Zn, NH, NM, NL);
    // P = Q @ Wp + bp  (gathered later)
    gemm128<<<dim3(6, 64), 256, 0, stream>>>(Q, Wp, bp, P, KCODES, DMODEL, DCODE);
    // sim + per-split argmax (MFMA bf16x3, race-fixed cross-wave merge)
    argmax_mfma<<<dim3(128, 8), 256, 0, stream>>>(NH, NM, NL, EH, EM, EL, pval, pidx);
    // exact fp32 rescore of 8 candidates -> idx
    merge_rescore<<<4096, 256, 0, stream>>>(Zn, emb, pidx, idxp);
    // out[n] = P[idx[n]]
    gather_k<<<16384, 192, 0, stream>>>(idxp, P, outF);
    // commitment loss
    loss_k<<<4096, 256, 0, stream>>>(Zn, emb, idxp, lossp);
    // codex one-hot (also wipes scratch region deterministically)
    onehot_k<<<16384, 256, 0, stream>>>(idxp, codex);
}

// Round 5
// 1162.366 us; speedup vs baseline: 1.2111x; 1.0922x over previous
//
#include <hip/hip_runtime.h>
#include <cstddef>
#include <cstdint>

typedef unsigned short u16;
typedef short bf16x8 __attribute__((ext_vector_type(8)));
typedef float f32x4 __attribute__((ext_vector_type(4)));

// Problem constants (B=16, S=1024, D=768, DC=64, K=8192)
#define NROW   16384
#define DMODEL 768
#define DCODE  64
#define KCODES 8192

// d_out layout (float element offsets): [out 16384*768][loss 1][codex 16384*8192]
#define OUT_LOSS  12582912
#define OUT_CODEX 12582913
// 16B-aligned scratch carved out of the codex region (fully overwritten by the
// one-hot writer at the end). All offsets in float units, multiples of 4.
#define S0        12582916
#define H_OFF     (S0)                        // 12582912 f
#define P_OFF     (H_OFF + 12582912)          // 6291456 f
#define ZN_OFF    (P_OFF + 6291456)           // 1048576 f
#define Q_OFF     (ZN_OFF + 1048576)          // 524288 f
#define ZH_OFF    (Q_OFF + 524288)            // u16 planes of Z: each 12582912 u16 = 6291456 f
#define ZM_OFF    (ZH_OFF + 6291456)
#define ZL_OFF    (ZM_OFF + 6291456)
#define W1H_OFF   (ZL_OFF + 6291456)          // W1^T planes: each 589824 u16 = 294912 f
#define W1M_OFF   (W1H_OFF + 294912)
#define W1L_OFF   (W1M_OFF + 294912)
#define NH_OFF    (W1L_OFF + 294912)          // Zn planes: each 1048576 u16 = 524288 f
#define NM_OFF    (NH_OFF + 524288)
#define NL_OFF    (NM_OFF + 524288)
#define EH_OFF    (NL_OFF + 524288)           // emb planes: each 524288 u16 = 262144 f
#define EM_OFF    (EH_OFF + 262144)
#define EL_OFF    (EM_OFF + 262144)

__device__ __forceinline__ u16 f2bf(float x) {
    unsigned u = __float_as_uint(x);
    u += 0x7fffu + ((u >> 16) & 1u);          // RTNE
    return (u16)(u >> 16);
}
__device__ __forceinline__ float bf2f(u16 h) {
    return __uint_as_float(((unsigned)h) << 16);
}

// async global->LDS, 16 B per lane. LDS dest is wave-uniform base + lane*16
// (m104/m108): callers must pass lds = base + lane*16 exactly.
typedef __attribute__((address_space(1))) const unsigned int gas_u32;
typedef __attribute__((address_space(3))) unsigned int las_u32;
__device__ __forceinline__ void gll16(const u16* g, u16* l) {
    __builtin_amdgcn_global_load_lds((gas_u32*)g, (las_u32*)l, 16, 0, 0);
}

// ---------------------------------------------------------------------------
// Split Z (fp32, 16384x768) into 3 bf16 planes (hi/mid/lo), elementwise x8.
// ---------------------------------------------------------------------------
__global__ __launch_bounds__(256) void split_z(const float* __restrict__ Z,
                                               u16* __restrict__ Ph,
                                               u16* __restrict__ Pm,
                                               u16* __restrict__ Pl) {
    const size_t g = (size_t)blockIdx.x * 256 + threadIdx.x;   // x8 elements
    const float4* zp = reinterpret_cast<const float4*>(Z) + g * 2;
    float4 a = zp[0], b = zp[1];
    float xs[8] = {a.x, a.y, a.z, a.w, b.x, b.y, b.z, b.w};
    union { u16 u[8]; uint4 v; } ph, pm, pl;
#pragma unroll
    for (int k = 0; k < 8; ++k) {
        float x = xs[k];
        u16 h = f2bf(x); float r = x - bf2f(h);
        u16 m = f2bf(r); float r2 = r - bf2f(m);
        u16 l = f2bf(r2);
        ph.u[k] = h; pm.u[k] = m; pl.u[k] = l;
    }
    *reinterpret_cast<uint4*>(Ph + g * 8) = ph.v;
    *reinterpret_cast<uint4*>(Pm + g * 8) = pm.v;
    *reinterpret_cast<uint4*>(Pl + g * 8) = pl.v;
}

// ---------------------------------------------------------------------------
// Split + transpose W1 (768x768): planes are W1^T [n][k] so B fragments read
// contiguous k. 32x32 LDS tile transpose.
// ---------------------------------------------------------------------------
__global__ __launch_bounds__(256) void split_w1t(const float* __restrict__ W1,
                                                 u16* __restrict__ Th,
                                                 u16* __restrict__ Tm,
                                                 u16* __restrict__ Tl) {
    __shared__ float tile[32][33];
    const int t = threadIdx.x;
    const int tc = t & 31, tr = t >> 5;          // tr 0..7
    const int k0 = blockIdx.y * 32, n0 = blockIdx.x * 32;
#pragma unroll
    for (int rr = 0; rr < 4; ++rr) {
        int r = tr * 4 + rr;
        tile[r][tc] = W1[(size_t)(k0 + r) * 768 + n0 + tc];
    }
    __syncthreads();
#pragma unroll
    for (int rr = 0; rr < 4; ++rr) {
        int n = n0 + tr * 4 + rr;
        int k = k0 + tc;
        float x = tile[tc][tr * 4 + rr];
        u16 h = f2bf(x); float r = x - bf2f(h);
        u16 m = f2bf(r); u16 l = f2bf(r - bf2f(m));
        Th[(size_t)n * 768 + k] = h;
        Tm[(size_t)n * 768 + k] = m;
        Tl[(size_t)n * 768 + k] = l;
    }
}

// ---------------------------------------------------------------------------
// One pass over emb (8192x64): write raw-emb bf16 splits (for sim MFMA) and
// Q = LN(emb)*gamma+beta (fp32, for the P projection). One wave per row.
// ---------------------------------------------------------------------------
__global__ __launch_bounds__(256) void qln_emb(const float* __restrict__ emb,
                                               const float* __restrict__ gamma,
                                               const float* __restrict__ beta,
                                               u16* __restrict__ Eh,
                                               u16* __restrict__ Em,
                                               u16* __restrict__ El,
                                               float* __restrict__ Q) {
    const int t = threadIdx.x;
    const int lane = t & 63;
    const int n = blockIdx.x * 4 + (t >> 6);
    float x = emb[(size_t)n * 64 + lane];
    u16 h = f2bf(x); float r = x - bf2f(h);
    u16 m = f2bf(r); u16 l = f2bf(r - bf2f(m));
    Eh[(size_t)n * 64 + lane] = h;
    Em[(size_t)n * 64 + lane] = m;
    El[(size_t)n * 64 + lane] = l;
    float mu = x;
#pragma unroll
    for (int off = 32; off > 0; off >>= 1) mu += __shfl_xor(mu, off, 64);
    mu *= (1.0f / 64.0f);
    float d = x - mu;
    float var = d * d;
#pragma unroll
    for (int off = 32; off > 0; off >>= 1) var += __shfl_xor(var, off, 64);
    var *= (1.0f / 64.0f);
    Q[(size_t)n * 64 + lane] = d * rsqrtf(var + 1e-5f) * gamma[lane] + beta[lane];
}

// ---------------------------------------------------------------------------
// GEMM1 via 6-product bf16x3 MFMA: H = tanh(Z @ W1 + b1).
// M=16384, N=768, K=768. BM=128, BN=128, BK=32.
// v2: global_load_lds(16B) staging into UNPADDED LDS (49152 B) with XOR chunk
// swizzle cc^((r>>1)&3) applied on the GLOBAL side (lane->LDS slot mapping is
// hardware-fixed to base+lane*16; lane->global mapping is free). Fragment
// ds_read_b128 bank aliasing = 2-way (free, m136). MFMA order identical to
// round 4 -> bitwise-identical results.
// ---------------------------------------------------------------------------
#define APL 4096   // u16 per 128x32 plane tile
__global__ __launch_bounds__(256, 2) void gemm1_mfma(
        const u16* __restrict__ Ah0, const u16* __restrict__ Am0, const u16* __restrict__ Al0,
        const u16* __restrict__ Bh0, const u16* __restrict__ Bm0, const u16* __restrict__ Bl0,
        const float* __restrict__ bias, float* __restrict__ H) {
    __shared__ u16 lds[6 * APL];          // A planes 0..2, B planes 3..5

    // XCD-grouped swizzle: the 6 col-blocks sharing one A row-tile land on one
    // XCD (A-tile L2 reuse). 768 blocks: xcd = b&7, i = b>>3 (0..95).
    const int b = blockIdx.x;
    const int xcd = b & 7, ii = b >> 3;
    const int row0 = (xcd * 16 + (ii & 15)) * 128;
    const int col0 = (ii >> 4) * 128;

    const int t = threadIdx.x;
    const int w = t >> 6, lane = t & 63, lm = lane & 15, q = lane >> 4;
    const int wr = (w >> 1) * 64, wc = (w & 1) * 64;

    const u16* Ap[3] = {Ah0, Am0, Al0};
    const u16* Bp[3] = {Bh0, Bm0, Bl0};

    // staging geometry: each wave-instruction covers 16 rows x 4 chunks(16B)
    const int sr  = lane >> 2;        // row within 16-row group
    const int scc = lane & 3;         // LDS chunk slot

    f32x4 acc[4][4];
#pragma unroll
    for (int i = 0; i < 4; ++i)
#pragma unroll
        for (int j = 0; j < 4; ++j) acc[i][j] = (f32x4){0.f, 0.f, 0.f, 0.f};

    for (int k0 = 0; k0 < 768; k0 += 32) {
        __syncthreads();
#pragma unroll
        for (int p = 0; p < 3; ++p) {
#pragma unroll
            for (int rr = 0; rr < 2; ++rr) {
                int g = rr * 4 + w;               // 16-row group 0..7
                int r = g * 16 + sr;              // local row 0..127
                int cg = scc ^ ((r >> 1) & 3);    // swizzled source chunk
                gll16(Ap[p] + (size_t)(row0 + r) * 768 + k0 + cg * 8,
                      &lds[p * APL + g * 512 + lane * 8]);
                gll16(Bp[p] + (size_t)(col0 + r) * 768 + k0 + cg * 8,
                      &lds[(3 + p) * APL + g * 512 + lane * 8]);
            }
        }
        __syncthreads();

        bf16x8 fah[4], fam[4], fal[4];
#pragma unroll
        for (int i = 0; i < 4; ++i) {
            int r = wr + i * 16 + lm;
            int off = r * 32 + ((q ^ ((r >> 1) & 3)) * 8);
            fah[i] = *reinterpret_cast<const bf16x8*>(&lds[0 * APL + off]);
            fam[i] = *reinterpret_cast<const bf16x8*>(&lds[1 * APL + off]);
            fal[i] = *reinterpret_cast<const bf16x8*>(&lds[2 * APL + off]);
        }
#pragma unroll
        for (int j = 0; j < 4; ++j) {
            int rb = wc + j * 16 + lm;
            int offb = rb * 32 + ((q ^ ((rb >> 1) & 3)) * 8);
            bf16x8 fbh = *reinterpret_cast<const bf16x8*>(&lds[3 * APL + offb]);
            bf16x8 fbm = *reinterpret_cast<const bf16x8*>(&lds[4 * APL + offb]);
            bf16x8 fbl = *reinterpret_cast<const bf16x8*>(&lds[5 * APL + offb]);
#pragma unroll
            for (int i = 0; i < 4; ++i) {
                f32x4 c = acc[i][j];
                c = __builtin_amdgcn_mfma_f32_16x16x32_bf16(fah[i], fbl, c, 0, 0, 0);
                c = __builtin_amdgcn_mfma_f32_16x16x32_bf16(fal[i], fbh, c, 0, 0, 0);
                c = __builtin_amdgcn_mfma_f32_16x16x32_bf16(fam[i], fbm, c, 0, 0, 0);
                c = __builtin_amdgcn_mfma_f32_16x16x32_bf16(fah[i], fbm, c, 0, 0, 0);
                c = __builtin_amdgcn_mfma_f32_16x16x32_bf16(fam[i], fbh, c, 0, 0, 0);
                c = __builtin_amdgcn_mfma_f32_16x16x32_bf16(fah[i], fbh, c, 0, 0, 0);
                acc[i][j] = c;
            }
        }
    }
    // epilogue: +bias, tanh, store
#pragma unroll
    for (int i = 0; i < 4; ++i)
#pragma unroll
        for (int j = 0; j < 4; ++j) {
            int col = col0 + wc + j * 16 + lm;
            float bv = bias[col];
#pragma unroll
            for (int r = 0; r < 4; ++r) {
                int row = row0 + wr + i * 16 + q * 4 + r;
                H[(size_t)row * 768 + col] = tanhf(acc[i][j][r] + bv);
            }
        }
}

// ---------------------------------------------------------------------------
// GEMM2 fused with l2norm: Zn = l2norm(H @ W2 + b2), also writes Zn bf16
// splits. M=16384, N=64(full), K=768. fp32 vector.
// v2: BM=64 -> 256 blocks (round 4's 128 blocks left half the CUs idle).
// ---------------------------------------------------------------------------
__global__ __launch_bounds__(256) void gemm2_l2(const float* __restrict__ A,
                                                const float* __restrict__ B,
                                                const float* __restrict__ bias,
                                                float* __restrict__ Zn,
                                                u16* __restrict__ Nh,
                                                u16* __restrict__ Nm,
                                                u16* __restrict__ Nl) {
    __shared__ float As[16][64];
    __shared__ float Bs[16][64];
    const int t    = threadIdx.x;
    const int row0 = blockIdx.x * 64;
    const int tx = t & 15, ty = t >> 4;
    const int ar = t >> 2, ac = (t & 3) << 2;
    const int br = t >> 4, bc = (t & 15) << 2;

    const float* Ap = A + (size_t)(row0 + ar) * 768 + ac;
    const float* Bp = B + (size_t)br * 64 + bc;

    float acc[4][4];
#pragma unroll
    for (int i = 0; i < 4; ++i)
#pragma unroll
        for (int j = 0; j < 4; ++j) acc[i][j] = 0.0f;

    for (int k0 = 0; k0 < 768; k0 += 16) {
        float4 a0 = *reinterpret_cast<const float4*>(Ap + k0);
        float4 b0 = *reinterpret_cast<const float4*>(Bp + (size_t)k0 * 64);
        __syncthreads();
        As[ac + 0][ar] = a0.x; As[ac + 1][ar] = a0.y;
        As[ac + 2][ar] = a0.z; As[ac + 3][ar] = a0.w;
        *reinterpret_cast<float4*>(&Bs[br][bc]) = b0;
        __syncthreads();
#pragma unroll
        for (int k = 0; k < 16; ++k) {
            float4 xa = *reinterpret_cast<const float4*>(&As[k][ty << 2]);
            float4 xb = *reinterpret_cast<const float4*>(&Bs[k][tx << 2]);
            float av[4] = {xa.x, xa.y, xa.z, xa.w};
            float bv[4] = {xb.x, xb.y, xb.z, xb.w};
#pragma unroll
            for (int i = 0; i < 4; ++i)
#pragma unroll
                for (int j = 0; j < 4; ++j)
                    acc[i][j] = fmaf(av[i], bv[j], acc[i][j]);
        }
    }
    const int c = tx << 2;
    const float4 bv4 = *reinterpret_cast<const float4*>(bias + c);
#pragma unroll
    for (int i = 0; i < 4; ++i) {
        float v0 = acc[i][0] + bv4.x;
        float v1 = acc[i][1] + bv4.y;
        float v2 = acc[i][2] + bv4.z;
        float v3 = acc[i][3] + bv4.w;
        float ss = v0 * v0 + v1 * v1 + v2 * v2 + v3 * v3;
#pragma unroll
        for (int msk = 1; msk <= 8; msk <<= 1) ss += __shfl_xor(ss, msk, 64);
        float sc = 1.0f / fmaxf(sqrtf(ss), 1e-12f);
        v0 *= sc; v1 *= sc; v2 *= sc; v3 *= sc;
        int r = row0 + (ty << 2) + i;
        float4 z = {v0, v1, v2, v3};
        *reinterpret_cast<float4*>(Zn + (size_t)r * 64 + c) = z;
        float vs[4] = {v0, v1, v2, v3};
        u16 hu[4], mu_[4], lu[4];
#pragma unroll
        for (int j = 0; j < 4; ++j) {
            u16 h = f2bf(vs[j]); float rr = vs[j] - bf2f(h);
            u16 m = f2bf(rr);    u16 l = f2bf(rr - bf2f(m));
            hu[j] = h; mu_[j] = m; lu[j] = l;
        }
        ushort4 hh = make_ushort4(hu[0], hu[1], hu[2], hu[3]);
        ushort4 mm = make_ushort4(mu_[0], mu_[1], mu_[2], mu_[3]);
        ushort4 ll = make_ushort4(lu[0], lu[1], lu[2], lu[3]);
        *reinterpret_cast<ushort4*>(Nh + (size_t)r * 64 + c) = hh;
        *reinterpret_cast<ushort4*>(Nm + (size_t)r * 64 + c) = mm;
        *reinterpret_cast<ushort4*>(Nl + (size_t)r * 64 + c) = ll;
    }
}

// ---------------------------------------------------------------------------
// Generic 128x128x16 fp32 tiled GEMM (used for P = Q @ Wp + bp, K=64).
// ---------------------------------------------------------------------------
__global__ __launch_bounds__(256) void gemm128(const float* __restrict__ A,
                                               const float* __restrict__ B,
                                               const float* __restrict__ bias,
                                               float* __restrict__ C,
                                               int M, int N, int K) {
    __shared__ float As[16][128];
    __shared__ float Bs[16][128];
    const int t    = threadIdx.x;
    const int row0 = blockIdx.y * 128;
    const int col0 = blockIdx.x * 128;
    const int tx = t & 15, ty = t >> 4;
    const int ar = t >> 2, ac = (t & 3) << 2;
    const int br = t >> 5, bc = (t & 31) << 2;

    const float* Ap0 = A + (size_t)(row0 + ar) * K + ac;
    const float* Ap1 = Ap0 + (size_t)64 * K;
    const float* Bp0 = B + (size_t)br * N + col0 + bc;
    const float* Bp1 = Bp0 + (size_t)8 * N;

    float acc[8][8];
#pragma unroll
    for (int i = 0; i < 8; ++i)
#pragma unroll
        for (int j = 0; j < 8; ++j) acc[i][j] = 0.0f;

    for (int k0 = 0; k0 < K; k0 += 16) {
        float4 a0 = *reinterpret_cast<const float4*>(Ap0 + k0);
        float4 a1 = *reinterpret_cast<const float4*>(Ap1 + k0);
        float4 b0 = *reinterpret_cast<const float4*>(Bp0 + (size_t)k0 * N);
        float4 b1 = *reinterpret_cast<const float4*>(Bp1 + (size_t)k0 * N);
        __syncthreads();
        As[ac + 0][ar] = a0.x; As[ac + 1][ar] = a0.y;
        As[ac + 2][ar] = a0.z; As[ac + 3][ar] = a0.w;
        As[ac + 0][ar + 64] = a1.x; As[ac + 1][ar + 64] = a1.y;
        As[ac + 2][ar + 64] = a1.z; As[ac + 3][ar + 64] = a1.w;
        *reinterpret_cast<float4*>(&Bs[br][bc])     = b0;
        *reinterpret_cast<float4*>(&Bs[br + 8][bc]) = b1;
        __syncthreads();
#pragma unroll
        for (int k = 0; k < 16; ++k) {
            float4 xa0 = *reinterpret_cast<const float4*>(&As[k][ty << 2]);
            float4 xa1 = *reinterpret_cast<const float4*>(&As[k][(ty << 2) + 64]);
            float4 xb0 = *reinterpret_cast<const float4*>(&Bs[k][tx << 2]);
            float4 xb1 = *reinterpret_cast<const float4*>(&Bs[k][(tx << 2) + 64]);
            float av[8] = {xa0.x, xa0.y, xa0.z, xa0.w, xa1.x, xa1.y, xa1.z, xa1.w};
            float bv[8] = {xb0.x, xb0.y, xb0.z, xb0.w, xb1.x, xb1.y, xb1.z, xb1.w};
#pragma unroll
            for (int i = 0; i < 8; ++i)
#pragma unroll
                for (int j = 0; j < 8; ++j)
                    acc[i][j] = fmaf(av[i], bv[j], acc[i][j]);
        }
    }
#pragma unroll
    for (int i = 0; i < 8; ++i) {
        int r = row0 + (ty << 2) + (i & 3) + ((i & 4) << 4);
        float* Crow = C + (size_t)r * N;
#pragma unroll
        for (int jh = 0; jh < 2; ++jh) {
            int cc = col0 + (tx << 2) + (jh << 6);
            float4 v;
            v.x = acc[i][jh * 4 + 0] + bias[cc + 0];
            v.y = acc[i][jh * 4 + 1] + bias[cc + 1];
            v.z = acc[i][jh * 4 + 2] + bias[cc + 2];
            v.w = acc[i][jh * 4 + 3] + bias[cc + 3];
            *reinterpret_cast<float4*>(Crow + cc) = v;
        }
    }
}

// ---------------------------------------------------------------------------
// Sim + argmax via 6-product bf16x3 MFMA. Grid (128 row-blocks, 8 splits).
// v2: B (emb planes) staged per 128-code chunk via global_load_lds(16B) into
// UNPADDED LDS with XOR chunk swizzle cc^(r&7) (2-way banks). A-fragments
// resident in registers (K=64). Cross-wave column-half winners merged through
// LDS (round-4 race fix). MFMA order identical to round 4.
// ---------------------------------------------------------------------------
#define EPL 8192   // u16 per 128x64 emb plane tile
__global__ __launch_bounds__(256, 2) void argmax_mfma(
        const u16* __restrict__ Zh, const u16* __restrict__ Zm, const u16* __restrict__ Zl,
        const u16* __restrict__ Eh, const u16* __restrict__ Em, const u16* __restrict__ El,
        float* __restrict__ pval, int* __restrict__ pidx) {
    __shared__ u16 Bsh[3 * EPL];          // 49152 B
    __shared__ float sv[128][2];          // +1024 B
    __shared__ int   si[128][2];          // +1024 B
    const int rb = blockIdx.x, split = blockIdx.y;
    const int row0 = rb * 128, cbase = split * 1024;
    const int t = threadIdx.x;
    const int w = t >> 6, lane = t & 63, lm = lane & 15, q = lane >> 4;
    const int wr = (w >> 1) * 64, wc = (w & 1) * 64;

    // staging geometry: each wave-instruction covers 8 rows x 8 chunks(16B)
    const int sr8 = lane >> 3;
    const int sc8 = lane & 7;

    // Resident A fragments: [plane][mtile][kstep]
    bf16x8 a[3][4][2];
#pragma unroll
    for (int i = 0; i < 4; ++i) {
        int row = row0 + wr + i * 16 + lm;
#pragma unroll
        for (int ks = 0; ks < 2; ++ks) {
            size_t off = (size_t)row * 64 + ks * 32 + q * 8;
            a[0][i][ks] = *reinterpret_cast<const bf16x8*>(Zh + off);
            a[1][i][ks] = *reinterpret_cast<const bf16x8*>(Zm + off);
            a[2][i][ks] = *reinterpret_cast<const bf16x8*>(Zl + off);
        }
    }

    float bval[4][4];
    int   bidx[4][4];
#pragma unroll
    for (int i = 0; i < 4; ++i)
#pragma unroll
        for (int r = 0; r < 4; ++r) { bval[i][r] = -3.0e38f; bidx[i][r] = 0; }

    for (int c = 0; c < 8; ++c) {
        const int code0 = cbase + c * 128;
        __syncthreads();
#pragma unroll
        for (int p = 0; p < 3; ++p) {
            const u16* Ep = (p == 0) ? Eh : ((p == 1) ? Em : El);
#pragma unroll
            for (int rr = 0; rr < 4; ++rr) {
                int g = rr * 4 + w;            // 8-row group 0..15
                int r = g * 8 + sr8;           // local code row 0..127
                int cg = sc8 ^ (r & 7);        // swizzled source chunk
                gll16(Ep + (size_t)(code0 + r) * 64 + cg * 8,
                      &Bsh[p * EPL + g * 512 + lane * 8]);
            }
        }
        __syncthreads();
#pragma unroll
        for (int j = 0; j < 4; ++j) {
            int rl = wc + j * 16 + lm;
            int nb = rl * 64;
            int s0 = (q ^ (rl & 7)) * 8;         // kstep 0 chunk
            int s1 = ((4 + q) ^ (rl & 7)) * 8;   // kstep 1 chunk
            bf16x8 eh0 = *reinterpret_cast<const bf16x8*>(&Bsh[0 * EPL + nb + s0]);
            bf16x8 eh1 = *reinterpret_cast<const bf16x8*>(&Bsh[0 * EPL + nb + s1]);
            bf16x8 em0 = *reinterpret_cast<const bf16x8*>(&Bsh[1 * EPL + nb + s0]);
            bf16x8 em1 = *reinterpret_cast<const bf16x8*>(&Bsh[1 * EPL + nb + s1]);
            bf16x8 el0 = *reinterpret_cast<const bf16x8*>(&Bsh[2 * EPL + nb + s0]);
            bf16x8 el1 = *reinterpret_cast<const bf16x8*>(&Bsh[2 * EPL + nb + s1]);
            int code = code0 + rl;
#pragma unroll
            for (int i = 0; i < 4; ++i) {
                f32x4 s = (f32x4){0.f, 0.f, 0.f, 0.f};
                s = __builtin_amdgcn_mfma_f32_16x16x32_bf16(a[0][i][0], el0, s, 0, 0, 0);
                s = __builtin_amdgcn_mfma_f32_16x16x32_bf16(a[2][i][0], eh0, s, 0, 0, 0);
                s = __builtin_amdgcn_mfma_f32_16x16x32_bf16(a[1][i][0], em0, s, 0, 0, 0);
                s = __builtin_amdgcn_mfma_f32_16x16x32_bf16(a[0][i][0], em0, s, 0, 0, 0);
                s = __builtin_amdgcn_mfma_f32_16x16x32_bf16(a[1][i][0], eh0, s, 0, 0, 0);
                s = __builtin_amdgcn_mfma_f32_16x16x32_bf16(a[0][i][0], eh0, s, 0, 0, 0);
                s = __builtin_amdgcn_mfma_f32_16x16x32_bf16(a[0][i][1], el1, s, 0, 0, 0);
                s = __builtin_amdgcn_mfma_f32_16x16x32_bf16(a[2][i][1], eh1, s, 0, 0, 0);
                s = __builtin_amdgcn_mfma_f32_16x16x32_bf16(a[1][i][1], em1, s, 0, 0, 0);
                s = __builtin_amdgcn_mfma_f32_16x16x32_bf16(a[0][i][1], em1, s, 0, 0, 0);
                s = __builtin_amdgcn_mfma_f32_16x16x32_bf16(a[1][i][1], eh1, s, 0, 0, 0);
                s = __builtin_amdgcn_mfma_f32_16x16x32_bf16(a[0][i][1], eh1, s, 0, 0, 0);
#pragma unroll
                for (int r = 0; r < 4; ++r)
                    if (s[r] > bval[i][r]) { bval[i][r] = s[r]; bidx[i][r] = code; }
            }
        }
    }
    // reduce over the 16 lanes sharing each row (lm bits 0..3), stash winner
#pragma unroll
    for (int i = 0; i < 4; ++i)
#pragma unroll
        for (int r = 0; r < 4; ++r) {
            float v = bval[i][r];
            int   id = bidx[i][r];
#pragma unroll
            for (int msk = 1; msk <= 8; msk <<= 1) {
                float ov = __shfl_xor(v, msk, 64);
                int   oid = __shfl_xor(id, msk, 64);
                if (ov > v || (ov == v && oid < id)) { v = ov; id = oid; }
            }
            if (lm == 0) {
                int rl = wr + i * 16 + q * 4 + r;
                sv[rl][w & 1] = v;
                si[rl][w & 1] = id;
            }
        }
    __syncthreads();
    if (t < 128) {
        float v0 = sv[t][0], v1 = sv[t][1];
        int   i0 = si[t][0], i1 = si[t][1];
        float bv; int bi;
        if (v1 > v0 || (v1 == v0 && i1 < i0)) { bv = v1; bi = i1; }
        else                                  { bv = v0; bi = i0; }
        pval[(size_t)(row0 + t) * 8 + split] = bv;
        pidx[(size_t)(row0 + t) * 8 + split] = bi;
    }
}

// ---------------------------------------------------------------------------
// Exact fp32 rescore of the 8 split candidates per row -> final idx.
// ---------------------------------------------------------------------------
__global__ __launch_bounds__(256) void merge_rescore(const float* __restrict__ Zn,
                                                     const float* __restrict__ emb,
                                                     const int* __restrict__ pidx,
                                                     int* __restrict__ idx) {
    __shared__ float sv[4][8];
    __shared__ int   si[4][8];
    const int t = threadIdx.x;
    const int w = t >> 6, lane = t & 63;
    const int row = blockIdx.x * 4 + w;
    const int cg = lane >> 3, s = lane & 7;
    int cand = pidx[(size_t)row * 8 + cg];
    const float4* zp = reinterpret_cast<const float4*>(Zn + (size_t)row * 64 + s * 8);
    const float4* ep = reinterpret_cast<const float4*>(emb + (size_t)cand * 64 + s * 8);
    float4 z0 = zp[0], z1 = zp[1], e0 = ep[0], e1 = ep[1];
    float acc = z0.x * e0.x + z0.y * e0.y + z0.z * e0.z + z0.w * e0.w
              + z1.x * e1.x + z1.y * e1.y + z1.z * e1.z + z1.w * e1.w;
#pragma unroll
    for (int msk = 1; msk <= 4; msk <<= 1) acc += __shfl_xor(acc, msk, 64);
    if (s == 0) { sv[w][cg] = acc; si[w][cg] = cand; }
    __syncthreads();
    if (lane == 0) {
        float bv = sv[w][0];
        int   bi = si[w][0];
#pragma unroll
        for (int cc = 1; cc < 8; ++cc) {
            float v = sv[w][cc];
            int   ii = si[w][cc];
            if (v > bv || (v == bv && ii < bi)) { bv = v; bi = ii; }
        }
        idx[row] = bi;
    }
}

// out[n,:] = P[idx[n],:]
__global__ __launch_bounds__(192) void gather_k(const int* __restrict__ idx,
                                                const float* __restrict__ P,
                                                float* __restrict__ out) {
    const int r = blockIdx.x;
    const int t = threadIdx.x;
    const int k = idx[r];
    float4 v = *reinterpret_cast<const float4*>(&P[(size_t)k * 768 + t * 4]);
    *reinterpret_cast<float4*>(&out[(size_t)r * 768 + t * 4]) = v;
}

// loss += ||emb[idx[n]] - Zn[n]||^2 / (NROW*DCODE)
__global__ __launch_bounds__(256) void loss_k(const float* __restrict__ Zn,
                                              const float* __restrict__ emb,
                                              const int* __restrict__ idx,
                                              float* __restrict__ loss) {
    const int t = threadIdx.x;
    const int lane = t & 63;
    const int n = blockIdx.x * 4 + (t >> 6);
    float d = Zn[(size_t)n * 64 + lane] - emb[(size_t)idx[n] * 64 + lane];
    float s = d * d;
#pragma unroll
    for (int off = 32; off > 0; off >>= 1) s += __shfl_xor(s, off, 64);
    if (lane == 0) atomicAdd(loss, s * (1.0f / (16384.0f * 64.0f)));
}

// codex_probs: write the full one-hot matrix in one streaming pass.
__global__ __launch_bounds__(256) void onehot_k(const int* __restrict__ idx,
                                                float* __restrict__ codex) {
    const int row = blockIdx.x;
    const int k = idx[row];
    float* base = codex + (size_t)row * 8192;
#pragma unroll
    for (int it = 0; it < 8; ++it) {
        int col = it * 1024 + threadIdx.x * 4;
        float4 v = {0.f, 0.f, 0.f, 0.f};
        unsigned d = (unsigned)(k - col);
        if (d < 4u) (&v.x)[d] = 1.0f;
        *reinterpret_cast<float4*>(base + col) = v;
    }
}

// ---------------------------------------------------------------------------
extern "C" void kernel_launch(void* const* d_in, const int* in_sizes, int n_in,
                              void* d_out, int out_size, void* d_ws, size_t ws_size,
                              hipStream_t stream) {
    const float* Z     = (const float*)d_in[0];
    const float* W1    = (const float*)d_in[1];
    const float* b1    = (const float*)d_in[2];
    const float* W2    = (const float*)d_in[3];
    const float* b2    = (const float*)d_in[4];
    const float* emb   = (const float*)d_in[5];
    const float* gamma = (const float*)d_in[6];
    const float* beta  = (const float*)d_in[7];
    const float* Wp    = (const float*)d_in[8];
    const float* bp    = (const float*)d_in[9];

    float* outF  = (float*)d_out;
    float* H     = outF + H_OFF;
    float* P     = outF + P_OFF;
    float* Zn    = outF + ZN_OFF;
    float* Q     = outF + Q_OFF;
    u16*   ZH    = (u16*)(outF + ZH_OFF);
    u16*   ZM    = (u16*)(outF + ZM_OFF);
    u16*   ZL    = (u16*)(outF + ZL_OFF);
    u16*   W1H   = (u16*)(outF + W1H_OFF);
    u16*   W1M   = (u16*)(outF + W1M_OFF);
    u16*   W1L   = (u16*)(outF + W1L_OFF);
    u16*   NH    = (u16*)(outF + NH_OFF);
    u16*   NM    = (u16*)(outF + NM_OFF);
    u16*   NL    = (u16*)(outF + NL_OFF);
    u16*   EH    = (u16*)(outF + EH_OFF);
    u16*   EM    = (u16*)(outF + EM_OFF);
    u16*   EL    = (u16*)(outF + EL_OFF);
    float* lossp = outF + OUT_LOSS;
    float* codex = outF + OUT_CODEX;

    float* pval = (float*)d_ws;                       // 16384*8 floats
    int*   pidx = (int*)((char*)d_ws + 524288);       // 16384*8 ints
    int*   idxp = (int*)((char*)d_ws + 1048576);      // 16384 ints

    hipMemsetAsync((void*)lossp, 0, 4, stream);

    // splits / preprocessing
    split_z<<<6144, 256, 0, stream>>>(Z, ZH, ZM, ZL);
    split_w1t<<<dim3(24, 24), 256, 0, stream>>>(W1, W1H, W1M, W1L);
    qln_emb<<<2048, 256, 0, stream>>>(emb, gamma, beta, EH, EM, EL, Q);
    // H = tanh(Z @ W1 + b1)   (MFMA bf16x3, async global_load_lds staging)
    gemm1_mfma<<<768, 256, 0, stream>>>(ZH, ZM, ZL, W1H, W1M, W1L, b1, H);
    // Zn = l2norm(H @ W2 + b2) + bf16 splits
    gemm2_l2<<<256, 256, 0, stream>>>(H, W2, b2, Zn, NH, NM, NL);
    // P = Q @ Wp + bp  (gathered later)
    gemm128<<<dim3(6, 64), 256, 0, stream>>>(Q, Wp, bp, P, KCODES, DMODEL, DCODE);
    // sim + per-split argmax (MFMA bf16x3, async staging)
    argmax_mfma<<<dim3(128, 8), 256, 0, stream>>>(NH, NM, NL, EH, EM, EL, pval, pidx);
    // exact fp32 rescore of 8 candidates -> idx
    merge_rescore<<<4096, 256, 0, stream>>>(Zn, emb, pidx, idxp);
    // out[n] = P[idx[n]]
    gather_k<<<16384, 192, 0, stream>>>(idxp, P, outF);
    // commitment loss
    loss_k<<<4096, 256, 0, stream>>>(Zn, emb, idxp, lossp);
    // codex one-hot (also wipes scratch region deterministically)
    onehot_k<<<16384, 256, 0, stream>>>(idxp, codex);
}